// Round 2
// baseline (1164.013 us; speedup 1.0000x reference)
//
#include <hip/hip_runtime.h>

#define BN 16384
#define TT 128
#define MM 4
#define SS 12
#define BLOCK 64
#define NSER (BLOCK / 4)    // 16 series per block (one wave)
#define TSTRIDE 145         // doubles per series region (R4-measured best banking)

// Single-wave workgroup; all cross-lane ops are within aligned lane-quads and
// use DPP quad_perm on the VALU pipe (no LDS/ds_bpermute). The only LDS
// cross-lane is the U-transpose; same-wave LDS ordering makes it safe with
// compiler-order fences (verified R5/R6: absmax identical to __syncthreads).
//
// R8: posterior form (R6 structure, 792us) + latency-exposure fixes:
//   - amdgpu_waves_per_eu(1,1): occupancy is grid-limited to 1 wave/SIMD, so
//     let the allocator use the whole 512-VGPR file for ILP (R7 showed the
//     heuristic otherwise caps at 128 and serializes).
//   - H (full + lane-local slice), R, and lane-local Q columns hoisted from
//     LDS into registers once, outside the t-loop (~230 fewer LDS ops/step).
//   - GEMM1 F-row loads explicitly double-buffered (fr[2][12]).

// quad_perm ctrl: broadcast from sub-lane R -> R*0x55; xor1 -> 0xB1; xor2 -> 0x4E
template<int CTRL>
__device__ __forceinline__ float dpp32(float v) {
    union { int i; float f; } u, o;
    u.f = v;
    o.i = __builtin_amdgcn_update_dpp(0, u.i, CTRL, 0xF, 0xF, true);
    return o.f;
}
template<int CTRL>
__device__ __forceinline__ double dpp64(double v) {
    union { double d; int i[2]; } u, o;
    u.d = v;
    o.i[0] = __builtin_amdgcn_update_dpp(0, u.i[0], CTRL, 0xF, 0xF, true);
    o.i[1] = __builtin_amdgcn_update_dpp(0, u.i[1], CTRL, 0xF, 0xF, true);
    return o.d;
}
__device__ __forceinline__ double qsum(double v) {  // sum over the quad
    v += dpp64<0xB1>(v);
    v += dpp64<0x4E>(v);
    return v;
}

__global__ void
__attribute__((amdgpu_flat_work_group_size(BLOCK, BLOCK)))
__attribute__((amdgpu_waves_per_eu(1, 1)))
kf_kernel(
    const float* __restrict__ inp,   // [B][T][M]
    const float* __restrict__ Fm,    // [S][S]
    const float* __restrict__ Hm,    // [M][S]
    const float* __restrict__ Qm,    // [S][S]
    const float* __restrict__ Rm,    // [M][M]
    const float* __restrict__ m0p,   // [B][S]
    const float* __restrict__ P0p,   // [B][S][S]
    float* __restrict__ outp)        // [T][B][M]
{
    __shared__ double Fd[SS * SS];
    __shared__ double tb[NSER * TSTRIDE];

    const int tid  = threadIdx.x;
    const int gid  = blockIdx.x * BLOCK + tid;
    const int b    = gid >> 2;        // series
    const int c    = gid & 3;         // quad sub-lane: owns P cols/rows {3c,3c+1,3c+2}
    const int sb   = tid >> 2;        // series-in-block
    const int col0 = 3 * c;

    for (int i = tid; i < SS * SS; i += BLOCK) Fd[i] = (double)Fm[i];

    // ---- loop-invariant constants in registers (statically indexed after
    // unroll; runtime col0 is resolved at load time, not reg-index time) ----
    double Hfull[MM][SS];             // H, full rows (for HP)
#pragma unroll
    for (int n = 0; n < MM; ++n)
#pragma unroll
        for (int s = 0; s < SS; ++s) Hfull[n][s] = (double)Hm[n * SS + s];

    double Hloc[MM][3];               // H, own 3 columns (for y / Su partials)
#pragma unroll
    for (int n = 0; n < MM; ++n)
#pragma unroll
        for (int jj = 0; jj < 3; ++jj) Hloc[n][jj] = (double)Hm[n * SS + col0 + jj];

    double Rfull[MM][MM];
#pragma unroll
    for (int n = 0; n < MM; ++n)
#pragma unroll
        for (int t2 = 0; t2 < MM; ++t2) Rfull[n][t2] = (double)Rm[n * MM + t2];

    double Qloc[SS][3];               // Q, own 3 columns (for GEMM2 init)
#pragma unroll
    for (int s = 0; s < SS; ++s)
#pragma unroll
        for (int jj = 0; jj < 3; ++jj) Qloc[s][jj] = (double)Qm[s * SS + col0 + jj];

    // persistent per-lane state: full mean + own 3 columns of symmetric P
    double m[SS];
#pragma unroll
    for (int s = 0; s < SS; ++s) m[s] = (double)m0p[b * SS + s];

    double P[SS][3];
#pragma unroll
    for (int s = 0; s < SS; ++s)
#pragma unroll
        for (int jj = 0; jj < 3; ++jj)
            P[s][jj] = (double)P0p[b * SS * SS + s * SS + col0 + jj];

    const float* op = inp + b * (TT * MM) + c;  // own measurement stream
    float obn = op[0];
    double* tser = &tb[sb * TSTRIDE];

    __syncthreads();  // F in LDS ready (once, outside the loop)

#pragma unroll 1
    for (int t = 0; t < TT; ++t) {
        __builtin_amdgcn_wave_barrier();  // order: prev Ur reads before new writes
        // ---------- GEMM1: U-row i = F[i,:]*P(local cols) -> LDS ----------
        // F-row loads double-buffered: row i+1 issues under row i's FMAs.
        {
            double fr[2][SS];
#pragma unroll
            for (int s = 0; s < SS; ++s) fr[0][s] = Fd[s];
#pragma unroll
            for (int i = 0; i < SS; ++i) {
                if (i + 1 < SS) {
#pragma unroll
                    for (int s = 0; s < SS; ++s)
                        fr[(i + 1) & 1][s] = Fd[(i + 1) * SS + s];
                }
                double u0 = 0.0, u1 = 0.0, u2 = 0.0;
#pragma unroll
                for (int s = 0; s < SS; ++s) {
                    u0 += fr[i & 1][s] * P[s][0];
                    u1 += fr[i & 1][s] * P[s][1];
                    u2 += fr[i & 1][s] * P[s][2];
                }
                tser[i * SS + col0 + 0] = u0;
                tser[i * SS + col0 + 1] = u1;
                tser[i * SS + col0 + 2] = u2;
            }
        }

        // ---------- own 3 rows of predicted mean: mvl[jj] = F[3c+jj,:] . m ----------
        double mvl[3];
#pragma unroll
        for (int jj = 0; jj < 3; ++jj) {
            double a = 0.0;
#pragma unroll
            for (int s = 0; s < SS; ++s) a += Fd[(col0 + jj) * SS + s] * m[s];
            mvl[jj] = a;
        }

        __builtin_amdgcn_wave_barrier();  // order: writes before Ur reads (HW LDS FIFO)

        // ---------- GEMM2 (split-K): P <- Q + U * F^T  (prior cov, in place) -------
#pragma unroll
        for (int h = 0; h < 2; ++h) {
            double Ur[3][6];
#pragma unroll
            for (int jj = 0; jj < 3; ++jj)
#pragma unroll
                for (int kk = 0; kk < 6; ++kk)
                    Ur[jj][kk] = tser[(col0 + jj) * SS + h * 6 + kk];
#pragma unroll
            for (int s = 0; s < SS; ++s) {
                double fr6[6];
#pragma unroll
                for (int kk = 0; kk < 6; ++kk) fr6[kk] = Fd[s * SS + h * 6 + kk];
                double p0 = (h == 0) ? Qloc[s][0] : P[s][0];
                double p1 = (h == 0) ? Qloc[s][1] : P[s][1];
                double p2 = (h == 0) ? Qloc[s][2] : P[s][2];
#pragma unroll
                for (int kk = 0; kk < 6; ++kk) {
                    p0 += Ur[0][kk] * fr6[kk];
                    p1 += Ur[1][kk] * fr6[kk];
                    p2 += Ur[2][kk] * fr6[kk];
                }
                P[s][0] = p0; P[s][1] = p1; P[s][2] = p2;
            }
        }

        // ---------- y[n] via quad DPP butterfly of partials ----------
        double y[MM];
#pragma unroll
        for (int n = 0; n < MM; ++n) {
            double py = Hloc[n][0] * mvl[0]
                      + Hloc[n][1] * mvl[1]
                      + Hloc[n][2] * mvl[2];
            y[n] = qsum(py);
        }
        double ysel = (c & 2) ? ((c & 1) ? y[3] : y[2]) : ((c & 1) ? y[1] : y[0]);
        outp[t * (BN * MM) + b * MM + c] = (float)ysel;

        float obc = obn;
        if (t + 1 < TT) obn = op[(t + 1) * MM];  // prefetch next obs

        // residuals all-local (obs shared by 4 cheap b32 DPP broadcasts)
        double r[MM];
        r[0] = (double)dpp32<0x00>(obc) - y[0];
        r[1] = (double)dpp32<0x55>(obc) - y[1];
        r[2] = (double)dpp32<0xAA>(obc) - y[2];
        r[3] = (double)dpp32<0xFF>(obc) - y[3];

        // ---------- HP = H * P_prior (local cols), H from registers ----------
        double HPl[MM][3];
#pragma unroll
        for (int n = 0; n < MM; ++n) {
            double h0 = 0.0, h1 = 0.0, h2 = 0.0;
#pragma unroll
            for (int s = 0; s < SS; ++s) {
                double hv = Hfull[n][s];
                h0 += hv * P[s][0]; h1 += hv * P[s][1]; h2 += hv * P[s][2];
            }
            HPl[n][0] = h0; HPl[n][1] = h1; HPl[n][2] = h2;
        }

        // ---------- innovation cov: local partial + quad DPP butterfly ----------
        double Su[10];
        {
            int u = 0;
#pragma unroll
            for (int n = 0; n < MM; ++n)
#pragma unroll
                for (int t2 = 0; t2 < MM; ++t2) {
                    if (t2 < n) continue;
                    double acc = HPl[n][0] * Hloc[t2][0]
                               + HPl[n][1] * Hloc[t2][1]
                               + HPl[n][2] * Hloc[t2][2];
                    Su[u] = qsum(acc) + Rfull[n][t2];
                    ++u;
                }
        }
        double s00 = Su[0], s01 = Su[1], s02 = Su[2], s03 = Su[3];
        double s11 = Su[4], s12 = Su[5], s13 = Su[6];
        double s22 = Su[7], s23 = Su[8], s33 = Su[9];

        // ---------- symmetric 4x4 inverse via 2x2 Schur (fp64) ----------
        double ra   = 1.0 / (s00 * s11 - s01 * s01);
        double ai00 = s11 * ra, ai01 = -s01 * ra, ai11 = s00 * ra;
        double w00 = ai00 * s02 + ai01 * s12;
        double w01 = ai00 * s03 + ai01 * s13;
        double w10 = ai01 * s02 + ai11 * s12;
        double w11 = ai01 * s03 + ai11 * s13;
        double e00 = s22 - (s02 * w00 + s12 * w10);
        double e01 = s23 - (s02 * w01 + s12 * w11);
        double e11 = s33 - (s03 * w01 + s13 * w11);
        double rmm = 1.0 / (e00 * e11 - e01 * e01);
        double q22 = e11 * rmm, q23 = -e01 * rmm, q33 = e00 * rmm;
        double x00 = w00 * q22 + w01 * q23;
        double x01 = w00 * q23 + w01 * q33;
        double x10 = w10 * q22 + w11 * q23;
        double x11 = w10 * q23 + w11 * q33;
        double q00 = ai00 + x00 * w00 + x01 * w01;
        double q01 = ai01 + x00 * w10 + x01 * w11;
        double q11 = ai11 + x10 * w10 + x11 * w11;
        double Qi[MM][MM] = {
            { q00,  q01,  -x00, -x01 },
            { q01,  q11,  -x10, -x11 },
            { -x00, -x10,  q22,  q23 },
            { -x01, -x11,  q23,  q33 }
        };

        // ---------- z = Sinv r ; mean update (no K materialized) ----------
        double z0 = Qi[0][0] * r[0] + Qi[0][1] * r[1] + Qi[0][2] * r[2] + Qi[0][3] * r[3];
        double z1 = Qi[1][0] * r[0] + Qi[1][1] * r[1] + Qi[1][2] * r[2] + Qi[1][3] * r[3];
        double z2 = Qi[2][0] * r[0] + Qi[2][1] * r[1] + Qi[2][2] * r[2] + Qi[2][3] * r[3];
        double z3 = Qi[3][0] * r[0] + Qi[3][1] * r[1] + Qi[3][2] * r[2] + Qi[3][3] * r[3];

        double pm[3];  // posterior mean, own 3 states
#pragma unroll
        for (int jj = 0; jj < 3; ++jj)
            pm[jj] = mvl[jj] + HPl[0][jj] * z0 + HPl[1][jj] * z1
                   + HPl[2][jj] * z2 + HPl[3][jj] * z3;

        // all-gather posterior mean via DPP broadcasts (state k lives on lane k/3)
        m[0]  = dpp64<0x00>(pm[0]);  m[1]  = dpp64<0x00>(pm[1]);  m[2]  = dpp64<0x00>(pm[2]);
        m[3]  = dpp64<0x55>(pm[0]);  m[4]  = dpp64<0x55>(pm[1]);  m[5]  = dpp64<0x55>(pm[2]);
        m[6]  = dpp64<0xAA>(pm[0]);  m[7]  = dpp64<0xAA>(pm[1]);  m[8]  = dpp64<0xAA>(pm[2]);
        m[9]  = dpp64<0xFF>(pm[0]);  m[10] = dpp64<0xFF>(pm[1]);  m[11] = dpp64<0xFF>(pm[2]);

        // ---------- covariance update: P -= (HP)^T Sinv (HP) ----------
        double G[MM][3];  // G = Sinv * HP (local cols)
#pragma unroll
        for (int n = 0; n < MM; ++n)
#pragma unroll
            for (int jj = 0; jj < 3; ++jj)
                G[n][jj] = Qi[n][0] * HPl[0][jj] + Qi[n][1] * HPl[1][jj]
                         + Qi[n][2] * HPl[2][jj] + Qi[n][3] * HPl[3][jj];

        // rows 3q+jr gathered from sub-lane q via DPP broadcast
#pragma unroll
        for (int jr = 0; jr < 3; ++jr) {
            {
                double h0 = dpp64<0x00>(HPl[0][jr]), h1 = dpp64<0x00>(HPl[1][jr]);
                double h2 = dpp64<0x00>(HPl[2][jr]), h3 = dpp64<0x00>(HPl[3][jr]);
#pragma unroll
                for (int jj = 0; jj < 3; ++jj)
                    P[jr][jj] -= h0 * G[0][jj] + h1 * G[1][jj] + h2 * G[2][jj] + h3 * G[3][jj];
            }
            {
                double h0 = dpp64<0x55>(HPl[0][jr]), h1 = dpp64<0x55>(HPl[1][jr]);
                double h2 = dpp64<0x55>(HPl[2][jr]), h3 = dpp64<0x55>(HPl[3][jr]);
#pragma unroll
                for (int jj = 0; jj < 3; ++jj)
                    P[3 + jr][jj] -= h0 * G[0][jj] + h1 * G[1][jj] + h2 * G[2][jj] + h3 * G[3][jj];
            }
            {
                double h0 = dpp64<0xAA>(HPl[0][jr]), h1 = dpp64<0xAA>(HPl[1][jr]);
                double h2 = dpp64<0xAA>(HPl[2][jr]), h3 = dpp64<0xAA>(HPl[3][jr]);
#pragma unroll
                for (int jj = 0; jj < 3; ++jj)
                    P[6 + jr][jj] -= h0 * G[0][jj] + h1 * G[1][jj] + h2 * G[2][jj] + h3 * G[3][jj];
            }
            {
                double h0 = dpp64<0xFF>(HPl[0][jr]), h1 = dpp64<0xFF>(HPl[1][jr]);
                double h2 = dpp64<0xFF>(HPl[2][jr]), h3 = dpp64<0xFF>(HPl[3][jr]);
#pragma unroll
                for (int jj = 0; jj < 3; ++jj)
                    P[9 + jr][jj] -= h0 * G[0][jj] + h1 * G[1][jj] + h2 * G[2][jj] + h3 * G[3][jj];
            }
        }
    }
}

extern "C" void kernel_launch(void* const* d_in, const int* in_sizes, int n_in,
                              void* d_out, int out_size, void* d_ws, size_t ws_size,
                              hipStream_t stream) {
    const float* inp = (const float*)d_in[0];
    const float* F   = (const float*)d_in[1];
    const float* H   = (const float*)d_in[2];
    const float* Q   = (const float*)d_in[3];
    const float* R   = (const float*)d_in[4];
    const float* m0  = (const float*)d_in[5];
    const float* P0  = (const float*)d_in[6];
    float* out = (float*)d_out;

    dim3 grid((BN * MM) / BLOCK), block(BLOCK);
    hipLaunchKernelGGL(kf_kernel, grid, block, 0, stream,
                       inp, F, H, Q, R, m0, P0, out);
}

// Round 3
// 820.968 us; speedup vs baseline: 1.4179x; 1.4179x over previous
//
#include <hip/hip_runtime.h>

#define BN 16384
#define TT 128
#define MM 4
#define SS 12
#define BLOCK 64
#define NSER (BLOCK / 4)    // 16 series per block (one wave)
#define TSTRIDE 145         // doubles per series region (R4-measured best banking)

// Single-wave workgroup; cross-lane via quad DPP; LDS only for F/H/Q/R consts
// and the U-transpose (same-wave LDS FIFO ordering + wave_barrier fences,
// verified earlier sessions).
//
// R9: Riccati PRIOR form (R7 math, passed) + forced stream interleave.
//   R7 lesson: prior form creates independence but compiler serializes it
//   (pressure-minimizing scheduler chose 128 VGPR). R8 lesson: hard cap is
//   256 VGPR, scratch spills beyond. Fix: zero-cost asm operand pins
//   ("+v") interleave GEMM2's four 6-row chunks with the 4x4 Schur inverse
//   stages, and pin region-1's update work (HP/Su/r/fmv) before GEMM1's
//   second half. Constants stay in LDS (no hoisting). Pressure est ~240.

// quad_perm ctrl: broadcast from sub-lane R -> R*0x55; xor1 -> 0xB1; xor2 -> 0x4E
template<int CTRL>
__device__ __forceinline__ float dpp32(float v) {
    union { int i; float f; } u, o;
    u.f = v;
    o.i = __builtin_amdgcn_update_dpp(0, u.i, CTRL, 0xF, 0xF, true);
    return o.f;
}
template<int CTRL>
__device__ __forceinline__ double dpp64(double v) {
    union { double d; int i[2]; } u, o;
    u.d = v;
    o.i[0] = __builtin_amdgcn_update_dpp(0, u.i[0], CTRL, 0xF, 0xF, true);
    o.i[1] = __builtin_amdgcn_update_dpp(0, u.i[1], CTRL, 0xF, 0xF, true);
    return o.d;
}
__device__ __forceinline__ double qsum(double v) {  // sum over the quad
    v += dpp64<0xB1>(v);
    v += dpp64<0x4E>(v);
    return v;
}

// scheduler pins: re-define listed values at this point (zero instructions).
#define PIN_P_LO() asm volatile("" : "+v"(P[0][0]),"+v"(P[0][1]),"+v"(P[0][2]), \
    "+v"(P[1][0]),"+v"(P[1][1]),"+v"(P[1][2]),"+v"(P[2][0]),"+v"(P[2][1]),"+v"(P[2][2]), \
    "+v"(P[3][0]),"+v"(P[3][1]),"+v"(P[3][2]),"+v"(P[4][0]),"+v"(P[4][1]),"+v"(P[4][2]), \
    "+v"(P[5][0]),"+v"(P[5][1]),"+v"(P[5][2]))
#define PIN_P_HI() asm volatile("" : "+v"(P[6][0]),"+v"(P[6][1]),"+v"(P[6][2]), \
    "+v"(P[7][0]),"+v"(P[7][1]),"+v"(P[7][2]),"+v"(P[8][0]),"+v"(P[8][1]),"+v"(P[8][2]), \
    "+v"(P[9][0]),"+v"(P[9][1]),"+v"(P[9][2]),"+v"(P[10][0]),"+v"(P[10][1]),"+v"(P[10][2]), \
    "+v"(P[11][0]),"+v"(P[11][1]),"+v"(P[11][2]))

__global__ __launch_bounds__(BLOCK, 1) void kf_kernel(
    const float* __restrict__ inp,   // [B][T][M]
    const float* __restrict__ Fm,    // [S][S]
    const float* __restrict__ Hm,    // [M][S]
    const float* __restrict__ Qm,    // [S][S]
    const float* __restrict__ Rm,    // [M][M]
    const float* __restrict__ m0p,   // [B][S]
    const float* __restrict__ P0p,   // [B][S][S]
    float* __restrict__ outp)        // [T][B][M]
{
    __shared__ double Fd[SS * SS];
    __shared__ double Hd[MM * SS];
    __shared__ double Qd[SS * SS];
    __shared__ double Rd[MM * MM];
    __shared__ double tb[NSER * TSTRIDE];

    const int tid  = threadIdx.x;
    const int gid  = blockIdx.x * BLOCK + tid;
    const int b    = gid >> 2;        // series
    const int c    = gid & 3;         // quad sub-lane: owns P cols {3c,3c+1,3c+2}
    const int sb   = tid >> 2;        // series-in-block
    const int col0 = 3 * c;

    for (int i = tid; i < SS * SS; i += BLOCK) {
        Fd[i] = (double)Fm[i];
        Qd[i] = (double)Qm[i];
    }
    if (tid < MM * SS) Hd[tid] = (double)Hm[tid];
    if (tid < MM * MM) Rd[tid] = (double)Rm[tid];

    // persistent per-lane state: own 3 columns of symmetric prior P
    double P[SS][3];
#pragma unroll
    for (int s = 0; s < SS; ++s)
#pragma unroll
        for (int jj = 0; jj < 3; ++jj)
            P[s][jj] = (double)P0p[b * SS * SS + s * SS + col0 + jj];

    double mtmp[SS];
#pragma unroll
    for (int s = 0; s < SS; ++s) mtmp[s] = (double)m0p[b * SS + s];

    const float* op = inp + b * (TT * MM) + c;  // own measurement stream
    float obn = op[0];
    double* tser = &tb[sb * TSTRIDE];

    __syncthreads();  // constants in LDS ready (once, outside the loop)

    // ======== initial predict: establish prior_0 = (F m0, F P0 F^T + Q) ========
#pragma unroll
    for (int i = 0; i < SS; ++i) {
        double fr[SS];
#pragma unroll
        for (int s = 0; s < SS; ++s) fr[s] = Fd[i * SS + s];
        double u0 = 0.0, u1 = 0.0, u2 = 0.0;
#pragma unroll
        for (int s = 0; s < SS; ++s) {
            u0 += fr[s] * P[s][0];
            u1 += fr[s] * P[s][1];
            u2 += fr[s] * P[s][2];
        }
        tser[i * SS + col0 + 0] = u0;
        tser[i * SS + col0 + 1] = u1;
        tser[i * SS + col0 + 2] = u2;
    }
    double pmv[3];
#pragma unroll
    for (int jj = 0; jj < 3; ++jj) {
        double a = 0.0;
#pragma unroll
        for (int s = 0; s < SS; ++s) a += Fd[(col0 + jj) * SS + s] * mtmp[s];
        pmv[jj] = a;
    }
    __builtin_amdgcn_wave_barrier();  // U writes before reads
#pragma unroll
    for (int h = 0; h < 2; ++h) {
        double Ur[3][6];
#pragma unroll
        for (int jj = 0; jj < 3; ++jj)
#pragma unroll
            for (int kk = 0; kk < 6; ++kk)
                Ur[jj][kk] = tser[(col0 + jj) * SS + h * 6 + kk];
#pragma unroll
        for (int s = 0; s < SS; ++s) {
            double fr6[6];
#pragma unroll
            for (int kk = 0; kk < 6; ++kk) fr6[kk] = Fd[s * SS + h * 6 + kk];
            double p0 = (h == 0) ? Qd[s * SS + col0 + 0] : P[s][0];
            double p1 = (h == 0) ? Qd[s * SS + col0 + 1] : P[s][1];
            double p2 = (h == 0) ? Qd[s * SS + col0 + 2] : P[s][2];
#pragma unroll
            for (int kk = 0; kk < 6; ++kk) {
                p0 += Ur[0][kk] * fr6[kk];
                p1 += Ur[1][kk] * fr6[kk];
                p2 += Ur[2][kk] * fr6[kk];
            }
            P[s][0] = p0; P[s][1] = p1; P[s][2] = p2;
        }
    }
    // lane-local prior mean (own 3 states) + full replicated prior mean
    double pml[3];
#pragma unroll
    for (int jj = 0; jj < 3; ++jj) pml[jj] = pmv[jj];
    double mvf[SS];
    mvf[0]  = dpp64<0x00>(pmv[0]);  mvf[1]  = dpp64<0x00>(pmv[1]);  mvf[2]  = dpp64<0x00>(pmv[2]);
    mvf[3]  = dpp64<0x55>(pmv[0]);  mvf[4]  = dpp64<0x55>(pmv[1]);  mvf[5]  = dpp64<0x55>(pmv[2]);
    mvf[6]  = dpp64<0xAA>(pmv[0]);  mvf[7]  = dpp64<0xAA>(pmv[1]);  mvf[8]  = dpp64<0xAA>(pmv[2]);
    mvf[9]  = dpp64<0xFF>(pmv[0]);  mvf[10] = dpp64<0xFF>(pmv[1]);  mvf[11] = dpp64<0xFF>(pmv[2]);

#pragma unroll 1
    for (int t = 0; t < TT; ++t) {
        __builtin_amdgcn_wave_barrier();  // order: prev Ur reads before new writes

        // ================= region 1 ======================================
        // ---- GEMM1 first half: U rows 0..5 = F[i,:]*P(local cols) -> LDS ----
#pragma unroll
        for (int i = 0; i < 6; ++i) {
            double fr[SS];
#pragma unroll
            for (int s = 0; s < SS; ++s) fr[s] = Fd[i * SS + s];
            double u0 = 0.0, u1 = 0.0, u2 = 0.0;
#pragma unroll
            for (int s = 0; s < SS; ++s) {
                u0 += fr[s] * P[s][0];
                u1 += fr[s] * P[s][1];
                u2 += fr[s] * P[s][2];
            }
            tser[i * SS + col0 + 0] = u0;
            tser[i * SS + col0 + 1] = u1;
            tser[i * SS + col0 + 2] = u2;
        }

        // ---- HP = H * P_prior (local cols) ----
        double HPl[MM][3];
#pragma unroll
        for (int n = 0; n < MM; ++n) {
            double h0 = 0.0, h1 = 0.0, h2 = 0.0;
#pragma unroll
            for (int s = 0; s < SS; ++s) {
                double hv = Hd[n * SS + s];
                h0 += hv * P[s][0]; h1 += hv * P[s][1]; h2 += hv * P[s][2];
            }
            HPl[n][0] = h0; HPl[n][1] = h1; HPl[n][2] = h2;
        }

        // ---- y[n] = H mvf via lane-local prior mean + quad butterfly ----
        double y[MM];
#pragma unroll
        for (int n = 0; n < MM; ++n) {
            double py = Hd[n * SS + col0 + 0] * pml[0]
                      + Hd[n * SS + col0 + 1] * pml[1]
                      + Hd[n * SS + col0 + 2] * pml[2];
            y[n] = qsum(py);
        }
        double ysel = (c & 2) ? ((c & 1) ? y[3] : y[2]) : ((c & 1) ? y[1] : y[0]);
        outp[t * (BN * MM) + b * MM + c] = (float)ysel;

        float obc = obn;
        if (t + 1 < TT) obn = op[(t + 1) * MM];  // prefetch next obs

        double r0v = (double)dpp32<0x00>(obc) - y[0];
        double r1v = (double)dpp32<0x55>(obc) - y[1];
        double r2v = (double)dpp32<0xAA>(obc) - y[2];
        double r3v = (double)dpp32<0xFF>(obc) - y[3];

        // ---- innovation cov: local partial + quad butterfly ----
        double Su[10];
        {
            int u = 0;
#pragma unroll
            for (int n = 0; n < MM; ++n)
#pragma unroll
                for (int t2 = 0; t2 < MM; ++t2) {
                    if (t2 < n) continue;
                    double acc = HPl[n][0] * Hd[t2 * SS + col0 + 0]
                               + HPl[n][1] * Hd[t2 * SS + col0 + 1]
                               + HPl[n][2] * Hd[t2 * SS + col0 + 2];
                    Su[u] = qsum(acc) + Rd[n * MM + t2];
                    ++u;
                }
        }
        double s00 = Su[0], s01 = Su[1], s02 = Su[2], s03 = Su[3];
        double s11 = Su[4], s12 = Su[5], s13 = Su[6];
        double s22 = Su[7], s23 = Su[8], s33 = Su[9];

        // ---- own 3 rows of F*mvf (prior-mean propagation) ----
        double fmv[3];
#pragma unroll
        for (int jj = 0; jj < 3; ++jj) {
            double a = 0.0;
#pragma unroll
            for (int s = 0; s < SS; ++s) a += Fd[(col0 + jj) * SS + s] * mvf[s];
            fmv[jj] = a;
        }

        // PIN: update-side work issued before GEMM1's second half; its DPP/LDS
        // latency hides under the 216 fp64 FMAs below.
        asm volatile("" : "+v"(HPl[0][0]),"+v"(HPl[0][1]),"+v"(HPl[0][2]),
                          "+v"(HPl[1][0]),"+v"(HPl[1][1]),"+v"(HPl[1][2]),
                          "+v"(HPl[2][0]),"+v"(HPl[2][1]),"+v"(HPl[2][2]),
                          "+v"(HPl[3][0]),"+v"(HPl[3][1]),"+v"(HPl[3][2]),
                          "+v"(s00),"+v"(s01),"+v"(s02),"+v"(s03),"+v"(s11),
                          "+v"(s12),"+v"(s13),"+v"(s22),"+v"(s23),"+v"(s33),
                          "+v"(r0v),"+v"(r1v),"+v"(r2v),"+v"(r3v),
                          "+v"(fmv[0]),"+v"(fmv[1]),"+v"(fmv[2]));
        PIN_P_LO(); PIN_P_HI();

        // ---- GEMM1 second half: U rows 6..11 ----
#pragma unroll
        for (int i = 6; i < SS; ++i) {
            double fr[SS];
#pragma unroll
            for (int s = 0; s < SS; ++s) fr[s] = Fd[i * SS + s];
            double u0 = 0.0, u1 = 0.0, u2 = 0.0;
#pragma unroll
            for (int s = 0; s < SS; ++s) {
                u0 += fr[s] * P[s][0];
                u1 += fr[s] * P[s][1];
                u2 += fr[s] * P[s][2];
            }
            tser[i * SS + col0 + 0] = u0;
            tser[i * SS + col0 + 1] = u1;
            tser[i * SS + col0 + 2] = u2;
        }

        __builtin_amdgcn_wave_barrier();  // order: U writes before Ur reads

        // ================= region 2: GEMM2 chunks ∥ inverse stages ==========
        double Ur0[3][6];
#pragma unroll
        for (int jj = 0; jj < 3; ++jj)
#pragma unroll
            for (int kk = 0; kk < 6; ++kk)
                Ur0[jj][kk] = tser[(col0 + jj) * SS + kk];

        // ---- A1: P[0..5] = Q + U*F^T (k-half 0) ----
#pragma unroll
        for (int s = 0; s < 6; ++s) {
            double fr6[6];
#pragma unroll
            for (int kk = 0; kk < 6; ++kk) fr6[kk] = Fd[s * SS + kk];
            double p0 = Qd[s * SS + col0 + 0];
            double p1 = Qd[s * SS + col0 + 1];
            double p2 = Qd[s * SS + col0 + 2];
#pragma unroll
            for (int kk = 0; kk < 6; ++kk) {
                p0 += Ur0[0][kk] * fr6[kk];
                p1 += Ur0[1][kk] * fr6[kk];
                p2 += Ur0[2][kk] * fr6[kk];
            }
            P[s][0] = p0; P[s][1] = p1; P[s][2] = p2;
        }

        // ---- B1: Schur stage 1 (2x2 inverse + w) ----
        double ra   = 1.0 / (s00 * s11 - s01 * s01);
        double ai00 = s11 * ra, ai01 = -s01 * ra, ai11 = s00 * ra;
        double w00 = ai00 * s02 + ai01 * s12;
        double w01 = ai00 * s03 + ai01 * s13;
        double w10 = ai01 * s02 + ai11 * s12;
        double w11 = ai01 * s03 + ai11 * s13;
        asm volatile("" : "+v"(w00),"+v"(w01),"+v"(w10),"+v"(w11),
                          "+v"(ai00),"+v"(ai01),"+v"(ai11));
        PIN_P_HI();   // A2 reads post-pin P[6..11] -> forced after B1

        // ---- A2: P[6..11] = Q + U*F^T (k-half 0) ----
#pragma unroll
        for (int s = 6; s < SS; ++s) {
            double fr6[6];
#pragma unroll
            for (int kk = 0; kk < 6; ++kk) fr6[kk] = Fd[s * SS + kk];
            double p0 = Qd[s * SS + col0 + 0];
            double p1 = Qd[s * SS + col0 + 1];
            double p2 = Qd[s * SS + col0 + 2];
#pragma unroll
            for (int kk = 0; kk < 6; ++kk) {
                p0 += Ur0[0][kk] * fr6[kk];
                p1 += Ur0[1][kk] * fr6[kk];
                p2 += Ur0[2][kk] * fr6[kk];
            }
            P[s][0] = p0; P[s][1] = p1; P[s][2] = p2;
        }

        // ---- B2: Schur stage 2 (complement + its inverse) ----
        double e00 = s22 - (s02 * w00 + s12 * w10);
        double e01 = s23 - (s02 * w01 + s12 * w11);
        double e11 = s33 - (s03 * w01 + s13 * w11);
        double rmm = 1.0 / (e00 * e11 - e01 * e01);
        double q22 = e11 * rmm, q23 = -e01 * rmm, q33 = e00 * rmm;
        asm volatile("" : "+v"(q22),"+v"(q23),"+v"(q33));
        PIN_P_LO();   // A3 rmw's post-pin P[0..5] -> forced after B2

        double Ur1[3][6];
#pragma unroll
        for (int jj = 0; jj < 3; ++jj)
#pragma unroll
            for (int kk = 0; kk < 6; ++kk)
                Ur1[jj][kk] = tser[(col0 + jj) * SS + 6 + kk];

        // ---- A3: P[0..5] += U*F^T (k-half 1) ----
#pragma unroll
        for (int s = 0; s < 6; ++s) {
            double fr6[6];
#pragma unroll
            for (int kk = 0; kk < 6; ++kk) fr6[kk] = Fd[s * SS + 6 + kk];
            double p0 = P[s][0], p1 = P[s][1], p2 = P[s][2];
#pragma unroll
            for (int kk = 0; kk < 6; ++kk) {
                p0 += Ur1[0][kk] * fr6[kk];
                p1 += Ur1[1][kk] * fr6[kk];
                p2 += Ur1[2][kk] * fr6[kk];
            }
            P[s][0] = p0; P[s][1] = p1; P[s][2] = p2;
        }

        // ---- B3: Schur stage 3 (x blocks, upper-left, z = Sinv r) ----
        double x00 = w00 * q22 + w01 * q23;
        double x01 = w00 * q23 + w01 * q33;
        double x10 = w10 * q22 + w11 * q23;
        double x11 = w10 * q23 + w11 * q33;
        double q00 = ai00 + x00 * w00 + x01 * w01;
        double q01 = ai01 + x00 * w10 + x01 * w11;
        double q11 = ai11 + x10 * w10 + x11 * w11;
        double z0 =  q00 * r0v + q01 * r1v - x00 * r2v - x01 * r3v;
        double z1 =  q01 * r0v + q11 * r1v - x10 * r2v - x11 * r3v;
        double z2 = -x00 * r0v - x10 * r1v + q22 * r2v + q23 * r3v;
        double z3 = -x01 * r0v - x11 * r1v + q23 * r2v + q33 * r3v;
        asm volatile("" : "+v"(z0),"+v"(z1),"+v"(z2),"+v"(z3),
                          "+v"(x00),"+v"(x01),"+v"(x10),"+v"(x11),
                          "+v"(q00),"+v"(q01),"+v"(q11));
        PIN_P_HI();   // A4 rmw's post-pin P[6..11] -> forced after B3

        // ---- A4: P[6..11] += U*F^T (k-half 1) ----
#pragma unroll
        for (int s = 6; s < SS; ++s) {
            double fr6[6];
#pragma unroll
            for (int kk = 0; kk < 6; ++kk) fr6[kk] = Fd[s * SS + 6 + kk];
            double p0 = P[s][0], p1 = P[s][1], p2 = P[s][2];
#pragma unroll
            for (int kk = 0; kk < 6; ++kk) {
                p0 += Ur1[0][kk] * fr6[kk];
                p1 += Ur1[1][kk] * fr6[kk];
                p2 += Ur1[2][kk] * fr6[kk];
            }
            P[s][0] = p0; P[s][1] = p1; P[s][2] = p2;
        }

        // ================= C: rank-4 correction + mean ======================
        double Qi[MM][MM] = {
            { q00,  q01,  -x00, -x01 },
            { q01,  q11,  -x10, -x11 },
            { -x00, -x10,  q22,  q23 },
            { -x01, -x11,  q23,  q33 }
        };

        // Vl = V(:, own cols), V = HP F^T; HP cols 3q+kk via quad broadcast q
        double Vl[MM][3];
        {
            double h00 = dpp64<0x00>(HPl[0][0]), h01 = dpp64<0x00>(HPl[0][1]), h02 = dpp64<0x00>(HPl[0][2]);
            double h10 = dpp64<0x00>(HPl[1][0]), h11 = dpp64<0x00>(HPl[1][1]), h12 = dpp64<0x00>(HPl[1][2]);
            double h20 = dpp64<0x00>(HPl[2][0]), h21 = dpp64<0x00>(HPl[2][1]), h22 = dpp64<0x00>(HPl[2][2]);
            double h30 = dpp64<0x00>(HPl[3][0]), h31 = dpp64<0x00>(HPl[3][1]), h32 = dpp64<0x00>(HPl[3][2]);
#pragma unroll
            for (int jj = 0; jj < 3; ++jj) {
                double f0 = Fd[(col0 + jj) * SS + 0], f1 = Fd[(col0 + jj) * SS + 1], f2 = Fd[(col0 + jj) * SS + 2];
                Vl[0][jj] = h00 * f0 + h01 * f1 + h02 * f2;
                Vl[1][jj] = h10 * f0 + h11 * f1 + h12 * f2;
                Vl[2][jj] = h20 * f0 + h21 * f1 + h22 * f2;
                Vl[3][jj] = h30 * f0 + h31 * f1 + h32 * f2;
            }
        }
        {
            double h00 = dpp64<0x55>(HPl[0][0]), h01 = dpp64<0x55>(HPl[0][1]), h02 = dpp64<0x55>(HPl[0][2]);
            double h10 = dpp64<0x55>(HPl[1][0]), h11 = dpp64<0x55>(HPl[1][1]), h12 = dpp64<0x55>(HPl[1][2]);
            double h20 = dpp64<0x55>(HPl[2][0]), h21 = dpp64<0x55>(HPl[2][1]), h22 = dpp64<0x55>(HPl[2][2]);
            double h30 = dpp64<0x55>(HPl[3][0]), h31 = dpp64<0x55>(HPl[3][1]), h32 = dpp64<0x55>(HPl[3][2]);
#pragma unroll
            for (int jj = 0; jj < 3; ++jj) {
                double f0 = Fd[(col0 + jj) * SS + 3], f1 = Fd[(col0 + jj) * SS + 4], f2 = Fd[(col0 + jj) * SS + 5];
                Vl[0][jj] += h00 * f0 + h01 * f1 + h02 * f2;
                Vl[1][jj] += h10 * f0 + h11 * f1 + h12 * f2;
                Vl[2][jj] += h20 * f0 + h21 * f1 + h22 * f2;
                Vl[3][jj] += h30 * f0 + h31 * f1 + h32 * f2;
            }
        }
        {
            double h00 = dpp64<0xAA>(HPl[0][0]), h01 = dpp64<0xAA>(HPl[0][1]), h02 = dpp64<0xAA>(HPl[0][2]);
            double h10 = dpp64<0xAA>(HPl[1][0]), h11 = dpp64<0xAA>(HPl[1][1]), h12 = dpp64<0xAA>(HPl[1][2]);
            double h20 = dpp64<0xAA>(HPl[2][0]), h21 = dpp64<0xAA>(HPl[2][1]), h22 = dpp64<0xAA>(HPl[2][2]);
            double h30 = dpp64<0xAA>(HPl[3][0]), h31 = dpp64<0xAA>(HPl[3][1]), h32 = dpp64<0xAA>(HPl[3][2]);
#pragma unroll
            for (int jj = 0; jj < 3; ++jj) {
                double f0 = Fd[(col0 + jj) * SS + 6], f1 = Fd[(col0 + jj) * SS + 7], f2 = Fd[(col0 + jj) * SS + 8];
                Vl[0][jj] += h00 * f0 + h01 * f1 + h02 * f2;
                Vl[1][jj] += h10 * f0 + h11 * f1 + h12 * f2;
                Vl[2][jj] += h20 * f0 + h21 * f1 + h22 * f2;
                Vl[3][jj] += h30 * f0 + h31 * f1 + h32 * f2;
            }
        }
        {
            double h00 = dpp64<0xFF>(HPl[0][0]), h01 = dpp64<0xFF>(HPl[0][1]), h02 = dpp64<0xFF>(HPl[0][2]);
            double h10 = dpp64<0xFF>(HPl[1][0]), h11 = dpp64<0xFF>(HPl[1][1]), h12 = dpp64<0xFF>(HPl[1][2]);
            double h20 = dpp64<0xFF>(HPl[2][0]), h21 = dpp64<0xFF>(HPl[2][1]), h22 = dpp64<0xFF>(HPl[2][2]);
            double h30 = dpp64<0xFF>(HPl[3][0]), h31 = dpp64<0xFF>(HPl[3][1]), h32 = dpp64<0xFF>(HPl[3][2]);
#pragma unroll
            for (int jj = 0; jj < 3; ++jj) {
                double f0 = Fd[(col0 + jj) * SS + 9], f1 = Fd[(col0 + jj) * SS + 10], f2 = Fd[(col0 + jj) * SS + 11];
                Vl[0][jj] += h00 * f0 + h01 * f1 + h02 * f2;
                Vl[1][jj] += h10 * f0 + h11 * f1 + h12 * f2;
                Vl[2][jj] += h20 * f0 + h21 * f1 + h22 * f2;
                Vl[3][jj] += h30 * f0 + h31 * f1 + h32 * f2;
            }
        }

        // G2 = Sinv * V (local cols)
        double G2[MM][3];
#pragma unroll
        for (int n = 0; n < MM; ++n)
#pragma unroll
            for (int jj = 0; jj < 3; ++jj)
                G2[n][jj] = Qi[n][0] * Vl[0][jj] + Qi[n][1] * Vl[1][jj]
                          + Qi[n][2] * Vl[2][jj] + Qi[n][3] * Vl[3][jj];

        // P -= V^T * G2 (rows 3q+kk via quad broadcast q)
        {
            double v00 = dpp64<0x00>(Vl[0][0]), v01 = dpp64<0x00>(Vl[0][1]), v02 = dpp64<0x00>(Vl[0][2]);
            double v10 = dpp64<0x00>(Vl[1][0]), v11 = dpp64<0x00>(Vl[1][1]), v12 = dpp64<0x00>(Vl[1][2]);
            double v20 = dpp64<0x00>(Vl[2][0]), v21 = dpp64<0x00>(Vl[2][1]), v22 = dpp64<0x00>(Vl[2][2]);
            double v30 = dpp64<0x00>(Vl[3][0]), v31 = dpp64<0x00>(Vl[3][1]), v32 = dpp64<0x00>(Vl[3][2]);
#pragma unroll
            for (int jj = 0; jj < 3; ++jj) {
                P[0][jj] -= v00 * G2[0][jj] + v10 * G2[1][jj] + v20 * G2[2][jj] + v30 * G2[3][jj];
                P[1][jj] -= v01 * G2[0][jj] + v11 * G2[1][jj] + v21 * G2[2][jj] + v31 * G2[3][jj];
                P[2][jj] -= v02 * G2[0][jj] + v12 * G2[1][jj] + v22 * G2[2][jj] + v32 * G2[3][jj];
            }
        }
        {
            double v00 = dpp64<0x55>(Vl[0][0]), v01 = dpp64<0x55>(Vl[0][1]), v02 = dpp64<0x55>(Vl[0][2]);
            double v10 = dpp64<0x55>(Vl[1][0]), v11 = dpp64<0x55>(Vl[1][1]), v12 = dpp64<0x55>(Vl[1][2]);
            double v20 = dpp64<0x55>(Vl[2][0]), v21 = dpp64<0x55>(Vl[2][1]), v22 = dpp64<0x55>(Vl[2][2]);
            double v30 = dpp64<0x55>(Vl[3][0]), v31 = dpp64<0x55>(Vl[3][1]), v32 = dpp64<0x55>(Vl[3][2]);
#pragma unroll
            for (int jj = 0; jj < 3; ++jj) {
                P[3][jj] -= v00 * G2[0][jj] + v10 * G2[1][jj] + v20 * G2[2][jj] + v30 * G2[3][jj];
                P[4][jj] -= v01 * G2[0][jj] + v11 * G2[1][jj] + v21 * G2[2][jj] + v31 * G2[3][jj];
                P[5][jj] -= v02 * G2[0][jj] + v12 * G2[1][jj] + v22 * G2[2][jj] + v32 * G2[3][jj];
            }
        }
        {
            double v00 = dpp64<0xAA>(Vl[0][0]), v01 = dpp64<0xAA>(Vl[0][1]), v02 = dpp64<0xAA>(Vl[0][2]);
            double v10 = dpp64<0xAA>(Vl[1][0]), v11 = dpp64<0xAA>(Vl[1][1]), v12 = dpp64<0xAA>(Vl[1][2]);
            double v20 = dpp64<0xAA>(Vl[2][0]), v21 = dpp64<0xAA>(Vl[2][1]), v22 = dpp64<0xAA>(Vl[2][2]);
            double v30 = dpp64<0xAA>(Vl[3][0]), v31 = dpp64<0xAA>(Vl[3][1]), v32 = dpp64<0xAA>(Vl[3][2]);
#pragma unroll
            for (int jj = 0; jj < 3; ++jj) {
                P[6][jj] -= v00 * G2[0][jj] + v10 * G2[1][jj] + v20 * G2[2][jj] + v30 * G2[3][jj];
                P[7][jj] -= v01 * G2[0][jj] + v11 * G2[1][jj] + v21 * G2[2][jj] + v31 * G2[3][jj];
                P[8][jj] -= v02 * G2[0][jj] + v12 * G2[1][jj] + v22 * G2[2][jj] + v32 * G2[3][jj];
            }
        }
        {
            double v00 = dpp64<0xFF>(Vl[0][0]), v01 = dpp64<0xFF>(Vl[0][1]), v02 = dpp64<0xFF>(Vl[0][2]);
            double v10 = dpp64<0xFF>(Vl[1][0]), v11 = dpp64<0xFF>(Vl[1][1]), v12 = dpp64<0xFF>(Vl[1][2]);
            double v20 = dpp64<0xFF>(Vl[2][0]), v21 = dpp64<0xFF>(Vl[2][1]), v22 = dpp64<0xFF>(Vl[2][2]);
            double v30 = dpp64<0xFF>(Vl[3][0]), v31 = dpp64<0xFF>(Vl[3][1]), v32 = dpp64<0xFF>(Vl[3][2]);
#pragma unroll
            for (int jj = 0; jj < 3; ++jj) {
                P[9][jj]  -= v00 * G2[0][jj] + v10 * G2[1][jj] + v20 * G2[2][jj] + v30 * G2[3][jj];
                P[10][jj] -= v01 * G2[0][jj] + v11 * G2[1][jj] + v21 * G2[2][jj] + v31 * G2[3][jj];
                P[11][jj] -= v02 * G2[0][jj] + v12 * G2[1][jj] + v22 * G2[2][jj] + v32 * G2[3][jj];
            }
        }

        // next prior mean: mvf' = F mvf + V^T z (own 3, then gather)
        double mvn[3];
#pragma unroll
        for (int jj = 0; jj < 3; ++jj)
            mvn[jj] = fmv[jj] + Vl[0][jj] * z0 + Vl[1][jj] * z1
                    + Vl[2][jj] * z2 + Vl[3][jj] * z3;

        pml[0] = mvn[0]; pml[1] = mvn[1]; pml[2] = mvn[2];
        mvf[0]  = dpp64<0x00>(mvn[0]);  mvf[1]  = dpp64<0x00>(mvn[1]);  mvf[2]  = dpp64<0x00>(mvn[2]);
        mvf[3]  = dpp64<0x55>(mvn[0]);  mvf[4]  = dpp64<0x55>(mvn[1]);  mvf[5]  = dpp64<0x55>(mvn[2]);
        mvf[6]  = dpp64<0xAA>(mvn[0]);  mvf[7]  = dpp64<0xAA>(mvn[1]);  mvf[8]  = dpp64<0xAA>(mvn[2]);
        mvf[9]  = dpp64<0xFF>(mvn[0]);  mvf[10] = dpp64<0xFF>(mvn[1]);  mvf[11] = dpp64<0xFF>(mvn[2]);
    }
}

extern "C" void kernel_launch(void* const* d_in, const int* in_sizes, int n_in,
                              void* d_out, int out_size, void* d_ws, size_t ws_size,
                              hipStream_t stream) {
    const float* inp = (const float*)d_in[0];
    const float* F   = (const float*)d_in[1];
    const float* H   = (const float*)d_in[2];
    const float* Q   = (const float*)d_in[3];
    const float* R   = (const float*)d_in[4];
    const float* m0  = (const float*)d_in[5];
    const float* P0  = (const float*)d_in[6];
    float* out = (float*)d_out;

    dim3 grid((BN * MM) / BLOCK), block(BLOCK);
    hipLaunchKernelGGL(kf_kernel, grid, block, 0, stream,
                       inp, F, H, Q, R, m0, P0, out);
}